// Round 5
// baseline (1317.903 us; speedup 1.0000x reference)
//
#include <hip/hip_runtime.h>

#define HC 128          // H*C = output dim
#define HEADS 8
#define CPH 16
#define EDIM 16
#define NG 8
#define GEPS 1e-5f
#define LOG2E 1.44269504f

// ---------- 16-lane (head) sum via DPP row rotates: pure VALU, no LDS ----------
__device__ __forceinline__ float head16_sum(float p) {
  int t;
  t = __builtin_amdgcn_update_dpp(0, __float_as_int(p), 0x128, 0xF, 0xF, true); // row_ror:8
  p += __int_as_float(t);
  t = __builtin_amdgcn_update_dpp(0, __float_as_int(p), 0x124, 0xF, 0xF, true); // row_ror:4
  p += __int_as_float(t);
  t = __builtin_amdgcn_update_dpp(0, __float_as_int(p), 0x122, 0xF, 0xF, true); // row_ror:2
  p += __int_as_float(t);
  t = __builtin_amdgcn_update_dpp(0, __float_as_int(p), 0x121, 0xF, 0xF, true); // row_ror:1
  p += __int_as_float(t);
  return p;
}

// ---------- K0: zero scratch ----------
__global__ void zero_k(float* __restrict__ p, size_t nwords) {
  size_t i = (size_t)blockIdx.x * 256 + threadIdx.x;
  if (i < nwords) p[i] = 0.f;
}

// ---------- K1: degree of real edges (by dst) + group-boundary marks ----------
__global__ void count_deg_mark(const int* __restrict__ ei, int* __restrict__ deg,
                               const int* __restrict__ batch, int* __restrict__ genc,
                               int E, int N) {
  int e = blockIdx.x * 256 + threadIdx.x;
  if (e >= E) return;
  atomicAdd(&deg[ei[E + e]], 1);
  if (e < N && (e == 0 || batch[e] != batch[e - 1])) {
    // encode start index i as (N - i) so zero-init means "empty group"
    atomicMax(&genc[batch[e]], N - e);
  }
}

// ---------- K2: xl = x@Wl+bl, xr = x@Wr+br — LDS-tiled GEMM ----------
// Block: 64 rows x 256 output cols (128 xl + 128 xr). 256 threads:
// 8 row-threads x 32 col-groups; each thread 8 rows x (1 xl float4 + 1 xr float4).
// W staged in LDS in 4 K-chunks of 32 (16KB + 16KB). Each ds_read_b128 of W
// feeds 32 FMAs -> VALU-bound, not latency-bound.
#define GEMM_ROWS 64
__global__ void __launch_bounds__(256) gemm_tiled(
    const float* __restrict__ x,
    const float* __restrict__ Wl, const float* __restrict__ bl,
    const float* __restrict__ Wr, const float* __restrict__ br,
    float* __restrict__ xl, float* __restrict__ xr, int N) {
  __shared__ float4 WL[32][32];   // [k within chunk][col float4 group]
  __shared__ float4 WR[32][32];
  int t = threadIdx.x;
  int cg = t & 31;                // col float4 group (0..31)
  int rt = t >> 5;                // row-thread (0..7)
  long row0 = (long)blockIdx.x * GEMM_ROWS + rt * 8;
  float4 bl4 = ((const float4*)bl)[cg];
  float4 br4 = ((const float4*)br)[cg];
  float4 accl[8], accr[8];
  #pragma unroll
  for (int r = 0; r < 8; ++r) { accl[r] = bl4; accr[r] = br4; }
  const float4* Wl4 = (const float4*)Wl;
  const float4* Wr4 = (const float4*)Wr;
  for (int kc = 0; kc < 4; ++kc) {
    __syncthreads();              // previous chunk fully consumed
    #pragma unroll
    for (int i = 0; i < 4; ++i) {
      int idx = t + i * 256;      // 0..1023
      int kr = idx >> 5, gg = idx & 31;
      WL[kr][gg] = Wl4[(kc * 32 + kr) * 32 + gg];
      WR[kr][gg] = Wr4[(kc * 32 + kr) * 32 + gg];
    }
    __syncthreads();
    #pragma unroll
    for (int k4 = 0; k4 < 8; ++k4) {
      float4 xv[8];
      #pragma unroll
      for (int r = 0; r < 8; ++r) {
        long row = row0 + r;
        xv[r] = (row < N) ? ((const float4*)(x + row * HC))[kc * 8 + k4]
                          : make_float4(0.f, 0.f, 0.f, 0.f);
      }
      #pragma unroll
      for (int kk = 0; kk < 4; ++kk) {
        int k = k4 * 4 + kk;
        float4 wl = WL[k][cg];
        float4 wr = WR[k][cg];
        #pragma unroll
        for (int r = 0; r < 8; ++r) {
          float xs = (&xv[r].x)[kk];
          accl[r].x = fmaf(xs, wl.x, accl[r].x);
          accl[r].y = fmaf(xs, wl.y, accl[r].y);
          accl[r].z = fmaf(xs, wl.z, accl[r].z);
          accl[r].w = fmaf(xs, wl.w, accl[r].w);
          accr[r].x = fmaf(xs, wr.x, accr[r].x);
          accr[r].y = fmaf(xs, wr.y, accr[r].y);
          accr[r].z = fmaf(xs, wr.z, accr[r].z);
          accr[r].w = fmaf(xs, wr.w, accr[r].w);
        }
      }
    }
  }
  #pragma unroll
  for (int r = 0; r < 8; ++r) {
    long row = row0 + r;
    if (row < N) {
      ((float4*)(xl + row * HC))[cg] = accl[r];
      ((float4*)(xr + row * HC))[cg] = accr[r];
    }
  }
}

// ---------- K3: scan of deg -> offsets (CSR) ----------
__global__ void scan1(const int* __restrict__ deg, int* __restrict__ bsum, int N) {
  __shared__ int s[256];
  int t = threadIdx.x;
  int n = blockIdx.x * 256 + t;
  s[t] = (n < N) ? deg[n] : 0;
  __syncthreads();
  for (int off = 128; off > 0; off >>= 1) {
    if (t < off) s[t] += s[t + off];
    __syncthreads();
  }
  if (t == 0) bsum[blockIdx.x] = s[0];
}
__global__ void scan2(const int* __restrict__ bsum, int* __restrict__ bofs, int nb,
                      int* __restrict__ offsets, int N,
                      const int* __restrict__ genc, int* __restrict__ gstart) {
  int run = 0;
  for (int b = 0; b < nb; ++b) { bofs[b] = run; run += bsum[b]; }
  offsets[N] = run;
  // decode group starts; suffix-min so empty groups collapse to 0-length
  int nxt = N;
  gstart[NG] = N;
  for (int g = NG - 1; g >= 0; --g) {
    int st = N - genc[g];
    if (st > nxt) st = nxt;
    gstart[g] = st;
    nxt = st;
  }
}
__global__ void scan3(const int* __restrict__ deg, const int* __restrict__ bofs,
                      int* __restrict__ offsets, int N) {
  __shared__ int s[256];
  int t = threadIdx.x;
  int n = blockIdx.x * 256 + t;
  int v = (n < N) ? deg[n] : 0;
  s[t] = v;
  __syncthreads();
  for (int off = 1; off < 256; off <<= 1) {
    int add = (t >= off) ? s[t - off] : 0;
    __syncthreads();
    s[t] += add;
    __syncthreads();
  }
  if (n < N) offsets[n] = bofs[blockIdx.x] + s[t] - v;  // exclusive
}

// ---------- K4: fill CSR with (edge, src) pairs; consumes deg ----------
__global__ void fill_csr(const int* __restrict__ ei, int* __restrict__ deg,
                         const int* __restrict__ offsets, int2* __restrict__ csr2, int E) {
  int e = blockIdx.x * 256 + threadIdx.x;
  if (e >= E) return;
  int d = ei[E + e];
  int pos = atomicSub(&deg[d], 1) - 1;
  csr2[offsets[d] + pos] = make_int2(e, ei[e]);
}

// ---------- K5: FUSED per-node attention + defer-max online softmax + agg ----------
// One 128-thread block per destination node. Self-loop (ea fill 'mean') merged
// at the end: ea_mean . We[:,ch] == mean over edges of (ea[e] . We[:,ch]).
// Logits kept in log2 space (att pre-scaled by log2e) so exp == v_exp_f32.
__global__ void __launch_bounds__(128) fused_node(
    const int* __restrict__ offsets, const int2* __restrict__ csr2,
    const float* __restrict__ ea,
    const float* __restrict__ xl, const float* __restrict__ xr,
    const float* __restrict__ We, const float* __restrict__ att,
    const float* __restrict__ x, const float* __restrict__ bias,
    float* __restrict__ out, int N) {
  int ch = threadIdx.x;
  long n = blockIdx.x;
  float we[EDIM];
  #pragma unroll
  for (int k = 0; k < EDIM; ++k) we[k] = We[k * HC + ch];
  float av = att[ch] * LOG2E;
  float av08 = 0.8f * av, av02 = 0.2f * av;
  float xl_n = xl[n * HC + ch];
  float xr_n = xr[n * HC + ch];
  int j0 = offsets[n], j1 = offsets[n + 1];

  float m = -INFINITY;   // running max (log2 space), uniform per 16-lane head
  float den = 0.f;       // running softmax denominator
  float acc = 0.f;       // running weighted feature sum (per channel)
  float eesum = 0.f;     // per-channel sum of (eev + xr_n); adjusted at end

  auto edge_update = [&](int e, float xls) {
    const float4* eap = (const float4*)(ea + (long)e * EDIM);
    float4 a0 = eap[0], a1 = eap[1], a2 = eap[2], a3 = eap[3];
    float mm = xr_n;
    mm = fmaf(a0.x, we[0], mm);  mm = fmaf(a0.y, we[1], mm);
    mm = fmaf(a0.z, we[2], mm);  mm = fmaf(a0.w, we[3], mm);
    mm = fmaf(a1.x, we[4], mm);  mm = fmaf(a1.y, we[5], mm);
    mm = fmaf(a1.z, we[6], mm);  mm = fmaf(a1.w, we[7], mm);
    mm = fmaf(a2.x, we[8], mm);  mm = fmaf(a2.y, we[9], mm);
    mm = fmaf(a2.z, we[10], mm); mm = fmaf(a2.w, we[11], mm);
    mm = fmaf(a3.x, we[12], mm); mm = fmaf(a3.y, we[13], mm);
    mm = fmaf(a3.z, we[14], mm); mm = fmaf(a3.w, we[15], mm);
    eesum += mm;                       // = eev + xr_n
    mm += xls;
    float p = fmaf(av08, fmaxf(mm, 0.f), av02 * mm);  // leaky(mm)*att*log2e
    p = head16_sum(p);                 // head logit, uniform in 16-lane group
    if (p > m + 11.5f) {               // rare: new max grew past threshold
      float sc = exp2f(m - p);
      acc = fmaf(acc, sc, xls);
      den = fmaf(den, sc, 1.f);
      m = p;
    } else {                           // common: single exp2, no rescale
      float w = exp2f(p - m);
      acc = fmaf(w, xls, acc);
      den += w;
    }
  };

  int j = j0;
  if ((j & 1) && j < j1) {             // peel to 16B-aligned pair boundary
    int2 es = csr2[j];
    int e = __builtin_amdgcn_readfirstlane(es.x);
    int s = __builtin_amdgcn_readfirstlane(es.y);
    edge_update(e, xl[(long)s * HC + ch]);
    ++j;
  }
  for (; j + 1 < j1; j += 2) {
    int4 q = *(const int4*)(csr2 + j);  // two (edge,src) pairs, one dwordx4
    int e0 = __builtin_amdgcn_readfirstlane(q.x);
    int s0 = __builtin_amdgcn_readfirstlane(q.y);
    int e1 = __builtin_amdgcn_readfirstlane(q.z);
    int s1 = __builtin_amdgcn_readfirstlane(q.w);
    float xls0 = xl[(long)s0 * HC + ch];
    float xls1 = xl[(long)s1 * HC + ch];
    edge_update(e0, xls0);
    edge_update(e1, xls1);
  }
  if (j < j1) {
    int2 es = csr2[j];
    int e = __builtin_amdgcn_readfirstlane(es.x);
    int s = __builtin_amdgcn_readfirstlane(es.y);
    edge_update(e, xl[(long)s * HC + ch]);
  }

  // ---- self-loop ----
  int deg = j1 - j0;
  float ee = (deg > 0) ? (eesum / (float)deg - xr_n) : 0.f;
  float mm = xl_n + xr_n + ee;
  float p = fmaf(av08, fmaxf(mm, 0.f), av02 * mm);
  p = head16_sum(p);
  if (p > m) {
    float sc = exp2f(m - p);
    acc = fmaf(acc, sc, xl_n);
    den = fmaf(den, sc, 1.f);
  } else {
    float w = exp2f(p - m);
    acc = fmaf(w, xl_n, acc);
    den += w;
  }

  out[n * HC + ch] = acc / den + bias[ch] + x[n * HC + ch];
}

// ---------- K6: GraphNorm segment sums (grid-parallel over group slices) ----------
#define GN_SLICES 32
__global__ void __launch_bounds__(128) gn_stats(
    const float* __restrict__ out, const int* __restrict__ gstart,
    float* __restrict__ gsum, float* __restrict__ gsq) {
  int g = blockIdx.x >> 5;
  int slice = blockIdx.x & 31;
  int s0 = gstart[g], s1 = gstart[g + 1];
  int cnt = s1 - s0;
  if (cnt <= 0) return;
  int chunk = (cnt + GN_SLICES - 1) / GN_SLICES;
  int lo = s0 + slice * chunk;
  int hi = lo + chunk; if (hi > s1) hi = s1;
  if (lo >= hi) return;
  int ch = threadIdx.x;
  float sum = 0.f, sq = 0.f;
  for (int nrow = lo; nrow < hi; ++nrow) {
    float v = out[(long)nrow * HC + ch];
    sum += v; sq += v * v;
  }
  atomicAdd(&gsum[g * HC + ch], sum);
  atomicAdd(&gsq[g * HC + ch], sq);
}

// ---------- K7: finalize mean / inv-std ----------
__global__ void gn_finalize(const float* __restrict__ gsum, const float* __restrict__ gsq,
                            const int* __restrict__ gstart, const float* __restrict__ gms,
                            float* __restrict__ msub, float* __restrict__ istd) {
  int t = blockIdx.x * 256 + threadIdx.x;
  if (t >= NG * HC) return;
  int g = t >> 7, ch = t & 127;
  float cnt = (float)(gstart[g + 1] - gstart[g]);
  if (cnt < 1.f) cnt = 1.f;
  float mean = gsum[t] / cnt;
  float c = gms[ch] * mean;              // the subtracted constant
  float ex2 = gsq[t] / cnt;
  float var = ex2 - 2.f * c * mean + c * c;   // E[(x-c)^2]
  msub[t] = c;
  istd[t] = rsqrtf(var + GEPS);
}

// ---------- K8: normalize + affine + ELU (float4) ----------
__global__ void gn_apply(float* __restrict__ out, const int* __restrict__ batch,
                         const float* __restrict__ msub, const float* __restrict__ istd,
                         const float* __restrict__ gnw, const float* __restrict__ gnb, int N) {
  long i = (long)blockIdx.x * 256 + threadIdx.x;     // float4 index
  if (i >= (long)N * 32) return;
  int c4 = (int)(i & 31);
  long n = i >> 5;
  int g = batch[n];
  float4 v = ((const float4*)out)[i];
  float4 ms = ((const float4*)msub)[g * 32 + c4];
  float4 is = ((const float4*)istd)[g * 32 + c4];
  float4 w  = ((const float4*)gnw)[c4];
  float4 b  = ((const float4*)gnb)[c4];
  float4 o;
  o.x = fmaf(w.x * (v.x - ms.x), is.x, b.x);
  o.y = fmaf(w.y * (v.y - ms.y), is.y, b.y);
  o.z = fmaf(w.z * (v.z - ms.z), is.z, b.z);
  o.w = fmaf(w.w * (v.w - ms.w), is.w, b.w);
  o.x = o.x > 0.f ? o.x : expm1f(o.x);
  o.y = o.y > 0.f ? o.y : expm1f(o.y);
  o.z = o.z > 0.f ? o.z : expm1f(o.z);
  o.w = o.w > 0.f ? o.w : expm1f(o.w);
  ((float4*)out)[i] = o;
}

extern "C" void kernel_launch(void* const* d_in, const int* in_sizes, int n_in,
                              void* d_out, int out_size, void* d_ws, size_t ws_size,
                              hipStream_t stream) {
  const float* x    = (const float*)d_in[0];
  const int*   ei   = (const int*)d_in[1];
  const float* ea   = (const float*)d_in[2];
  const int*   batch= (const int*)d_in[3];
  const float* Wl   = (const float*)d_in[4];
  const float* bl   = (const float*)d_in[5];
  const float* Wr   = (const float*)d_in[6];
  const float* br   = (const float*)d_in[7];
  const float* We   = (const float*)d_in[8];
  const float* att  = (const float*)d_in[9];
  const float* bias = (const float*)d_in[10];
  const float* gnw  = (const float*)d_in[11];
  const float* gnb  = (const float*)d_in[12];
  const float* gms  = (const float*)d_in[13];
  int N = in_sizes[0] / HC;
  int E = in_sizes[2] / EDIM;
  float* out = (float*)d_out;
  (void)n_in; (void)out_size; (void)ws_size;

  // ---- workspace carve-up (4-byte words, 16B aligned blocks) ----
  float* wsf = (float*)d_ws;
  size_t off = 0;
  auto alloc = [&](size_t words) -> float* {
    float* p = wsf + off;
    off += (words + 3) & ~(size_t)3;
    return p;
  };
  int*      deg     = (int*)alloc(N);
  float*    gsum    = alloc(NG * HC);
  float*    gsq     = alloc(NG * HC);
  int*      genc    = (int*)alloc(NG);
  size_t zero_words = off;                 // everything above starts at 0
  int*      gstart  = (int*)alloc(NG + 1);
  float*    msub    = alloc(NG * HC);
  float*    istd    = alloc(NG * HC);
  int*      bsum    = (int*)alloc(256);
  int*      bofs    = (int*)alloc(256);
  int*      offsets = (int*)alloc((size_t)N + 1);
  float*    xl      = alloc((size_t)N * HC);
  float*    xr      = alloc((size_t)N * HC);
  int2*     csr2    = (int2*)alloc((size_t)E * 2);

  int nb = (N + 255) / 256;   // scan blocks (<=256 by construction for N<=65536)

  zero_k<<<(unsigned)((zero_words + 255) / 256), 256, 0, stream>>>(wsf, zero_words);
  count_deg_mark<<<(E + 255) / 256, 256, 0, stream>>>(ei, deg, batch, genc, E, N);
  gemm_tiled<<<(N + GEMM_ROWS - 1) / GEMM_ROWS, 256, 0, stream>>>(x, Wl, bl, Wr, br, xl, xr, N);
  scan1<<<nb, 256, 0, stream>>>(deg, bsum, N);
  scan2<<<1, 1, 0, stream>>>(bsum, bofs, nb, offsets, N, genc, gstart);
  scan3<<<nb, 256, 0, stream>>>(deg, bofs, offsets, N);
  fill_csr<<<(E + 255) / 256, 256, 0, stream>>>(ei, deg, offsets, csr2, E);
  fused_node<<<N, 128, 0, stream>>>(offsets, csr2, ea, xl, xr, We, att, x, bias, out, N);
  gn_stats<<<NG * GN_SLICES, 128, 0, stream>>>(out, gstart, gsum, gsq);
  gn_finalize<<<(NG * HC + 255) / 256, 256, 0, stream>>>(gsum, gsq, gstart, gms, msub, istd);
  {
    long tot = (long)N * 32;
    gn_apply<<<(unsigned)((tot + 255) / 256), 256, 0, stream>>>(out, batch, msub, istd, gnw, gnb, N);
  }
}

// Round 6
// 400.084 us; speedup vs baseline: 3.2941x; 3.2941x over previous
//
#include <hip/hip_runtime.h>

#define HC 128          // H*C = output dim
#define HEADS 8
#define CPH 16
#define EDIM 16
#define NG 8
#define GEPS 1e-5f
#define LOG2E 1.44269504f

// ---------- 16-lane (head) sum via DPP row rotates: pure VALU, no LDS ----------
__device__ __forceinline__ float head16_sum(float p) {
  int t;
  t = __builtin_amdgcn_update_dpp(0, __float_as_int(p), 0x128, 0xF, 0xF, true); // row_ror:8
  p += __int_as_float(t);
  t = __builtin_amdgcn_update_dpp(0, __float_as_int(p), 0x124, 0xF, 0xF, true); // row_ror:4
  p += __int_as_float(t);
  t = __builtin_amdgcn_update_dpp(0, __float_as_int(p), 0x122, 0xF, 0xF, true); // row_ror:2
  p += __int_as_float(t);
  t = __builtin_amdgcn_update_dpp(0, __float_as_int(p), 0x121, 0xF, 0xF, true); // row_ror:1
  p += __int_as_float(t);
  return p;
}

// ---------- K0: zero scratch ----------
__global__ void zero_k(float* __restrict__ p, size_t nwords) {
  size_t i = (size_t)blockIdx.x * 256 + threadIdx.x;
  if (i < nwords) p[i] = 0.f;
}

// ---------- K1: degree of real edges (by dst) + group-boundary marks ----------
__global__ void count_deg_mark(const int* __restrict__ ei, int* __restrict__ deg,
                               const int* __restrict__ batch, int* __restrict__ genc,
                               int E, int N) {
  int e = blockIdx.x * 256 + threadIdx.x;
  if (e >= E) return;
  atomicAdd(&deg[ei[E + e]], 1);
  if (e < N && (e == 0 || batch[e] != batch[e - 1])) {
    // encode start index i as (N - i) so zero-init means "empty group"
    atomicMax(&genc[batch[e]], N - e);
  }
}

// ---------- K2: xl = x@Wl+bl, xr = x@Wr+br — LDS-tiled GEMM, all-LDS inner loop ----
// Block: 32 rows x 256 output cols (128 xl + 128 xr). 256 threads =
// 8 row-threads x 32 col-groups; each thread 4 rows x (1 xl + 1 xr float4).
// Per K-chunk (32): W staged in LDS (32KB) AND x staged in LDS (4KB) so the
// inner loop is pure LDS+VALU: acc 32 VGPR + xv 16 -> no spills (R5 lesson:
// 8-row tile + in-loop global x loads => 256 VGPR + 1.3GB scratch spill).
#define GEMM_ROWS 32
__global__ void __launch_bounds__(256) gemm_tiled(
    const float* __restrict__ x,
    const float* __restrict__ Wl, const float* __restrict__ bl,
    const float* __restrict__ Wr, const float* __restrict__ br,
    float* __restrict__ xl, float* __restrict__ xr, int N) {
  __shared__ float4 WL[32][32];   // [k within chunk][col float4 group] 16KB
  __shared__ float4 WR[32][32];   // 16KB
  __shared__ float4 XS[GEMM_ROWS][8];  // [local row][k4 within chunk] 4KB
  int t = threadIdx.x;
  int cg = t & 31;                // col float4 group (0..31)
  int rt = t >> 5;                // row-thread (0..7), owns rows rt*4..rt*4+3
  int row0 = blockIdx.x * GEMM_ROWS;
  float4 bl4 = ((const float4*)bl)[cg];
  float4 br4 = ((const float4*)br)[cg];
  float4 accl[4], accr[4];
  #pragma unroll
  for (int r = 0; r < 4; ++r) { accl[r] = bl4; accr[r] = br4; }
  const float4* Wl4 = (const float4*)Wl;
  const float4* Wr4 = (const float4*)Wr;
  const float4* x4  = (const float4*)x;
  // x staging coords for this thread (one float4 per chunk)
  int srow = t >> 3, sk4 = t & 7;
  long sgrow = row0 + srow;
  for (int kc = 0; kc < 4; ++kc) {
    __syncthreads();              // previous chunk fully consumed
    #pragma unroll
    for (int i = 0; i < 4; ++i) {
      int idx = t + i * 256;      // 0..1023
      int kr = idx >> 5, gg = idx & 31;
      WL[kr][gg] = Wl4[(kc * 32 + kr) * 32 + gg];
      WR[kr][gg] = Wr4[(kc * 32 + kr) * 32 + gg];
    }
    XS[srow][sk4] = (sgrow < N) ? x4[sgrow * 32 + kc * 8 + sk4]
                                : make_float4(0.f, 0.f, 0.f, 0.f);
    __syncthreads();
    #pragma unroll
    for (int k4 = 0; k4 < 8; ++k4) {
      float4 xv[4];
      #pragma unroll
      for (int r = 0; r < 4; ++r) xv[r] = XS[rt * 4 + r][k4];
      #pragma unroll
      for (int kk = 0; kk < 4; ++kk) {
        float4 wl = WL[k4 * 4 + kk][cg];
        float4 wr = WR[k4 * 4 + kk][cg];
        #pragma unroll
        for (int r = 0; r < 4; ++r) {
          float xs = (&xv[r].x)[kk];
          accl[r].x = fmaf(xs, wl.x, accl[r].x);
          accl[r].y = fmaf(xs, wl.y, accl[r].y);
          accl[r].z = fmaf(xs, wl.z, accl[r].z);
          accl[r].w = fmaf(xs, wl.w, accl[r].w);
          accr[r].x = fmaf(xs, wr.x, accr[r].x);
          accr[r].y = fmaf(xs, wr.y, accr[r].y);
          accr[r].z = fmaf(xs, wr.z, accr[r].z);
          accr[r].w = fmaf(xs, wr.w, accr[r].w);
        }
      }
    }
  }
  #pragma unroll
  for (int r = 0; r < 4; ++r) {
    long row = row0 + rt * 4 + r;
    if (row < N) {
      ((float4*)(xl + row * HC))[cg] = accl[r];
      ((float4*)(xr + row * HC))[cg] = accr[r];
    }
  }
}

// ---------- K3: scan of deg -> offsets (CSR) ----------
__global__ void scan1(const int* __restrict__ deg, int* __restrict__ bsum, int N) {
  __shared__ int s[256];
  int t = threadIdx.x;
  int n = blockIdx.x * 256 + t;
  s[t] = (n < N) ? deg[n] : 0;
  __syncthreads();
  for (int off = 128; off > 0; off >>= 1) {
    if (t < off) s[t] += s[t + off];
    __syncthreads();
  }
  if (t == 0) bsum[blockIdx.x] = s[0];
}
__global__ void scan2(const int* __restrict__ bsum, int* __restrict__ bofs, int nb,
                      int* __restrict__ offsets, int N,
                      const int* __restrict__ genc, int* __restrict__ gstart) {
  int run = 0;
  for (int b = 0; b < nb; ++b) { bofs[b] = run; run += bsum[b]; }
  offsets[N] = run;
  // decode group starts; suffix-min so empty groups collapse to 0-length
  int nxt = N;
  gstart[NG] = N;
  for (int g = NG - 1; g >= 0; --g) {
    int st = N - genc[g];
    if (st > nxt) st = nxt;
    gstart[g] = st;
    nxt = st;
  }
}
__global__ void scan3(const int* __restrict__ deg, const int* __restrict__ bofs,
                      int* __restrict__ offsets, int N) {
  __shared__ int s[256];
  int t = threadIdx.x;
  int n = blockIdx.x * 256 + t;
  int v = (n < N) ? deg[n] : 0;
  s[t] = v;
  __syncthreads();
  for (int off = 1; off < 256; off <<= 1) {
    int add = (t >= off) ? s[t - off] : 0;
    __syncthreads();
    s[t] += add;
    __syncthreads();
  }
  if (n < N) offsets[n] = bofs[blockIdx.x] + s[t] - v;  // exclusive
}

// ---------- K4: fill CSR with (edge, src) pairs; consumes deg ----------
__global__ void fill_csr(const int* __restrict__ ei, int* __restrict__ deg,
                         const int* __restrict__ offsets, int2* __restrict__ csr2, int E) {
  int e = blockIdx.x * 256 + threadIdx.x;
  if (e >= E) return;
  int d = ei[E + e];
  int pos = atomicSub(&deg[d], 1) - 1;
  csr2[offsets[d] + pos] = make_int2(e, ei[e]);
}

// ---------- K5: FUSED per-node attention + defer-max online softmax + agg ----------
// One 128-thread block per destination node. Self-loop (ea fill 'mean') merged
// at the end: ea_mean . We[:,ch] == mean over edges of (ea[e] . We[:,ch]).
// Logits kept in log2 space (att pre-scaled by log2e) so exp == v_exp_f32.
__global__ void __launch_bounds__(128) fused_node(
    const int* __restrict__ offsets, const int2* __restrict__ csr2,
    const float* __restrict__ ea,
    const float* __restrict__ xl, const float* __restrict__ xr,
    const float* __restrict__ We, const float* __restrict__ att,
    const float* __restrict__ x, const float* __restrict__ bias,
    float* __restrict__ out, int N) {
  int ch = threadIdx.x;
  long n = blockIdx.x;
  float we[EDIM];
  #pragma unroll
  for (int k = 0; k < EDIM; ++k) we[k] = We[k * HC + ch];
  float av = att[ch] * LOG2E;
  float av08 = 0.8f * av, av02 = 0.2f * av;
  float xl_n = xl[n * HC + ch];
  float xr_n = xr[n * HC + ch];
  int j0 = offsets[n], j1 = offsets[n + 1];

  float m = -INFINITY;   // running max (log2 space), uniform per 16-lane head
  float den = 0.f;       // running softmax denominator
  float acc = 0.f;       // running weighted feature sum (per channel)
  float eesum = 0.f;     // per-channel sum of (eev + xr_n); adjusted at end

  auto edge_update = [&](int e, float xls) {
    const float4* eap = (const float4*)(ea + (long)e * EDIM);
    float4 a0 = eap[0], a1 = eap[1], a2 = eap[2], a3 = eap[3];
    float mm = xr_n;
    mm = fmaf(a0.x, we[0], mm);  mm = fmaf(a0.y, we[1], mm);
    mm = fmaf(a0.z, we[2], mm);  mm = fmaf(a0.w, we[3], mm);
    mm = fmaf(a1.x, we[4], mm);  mm = fmaf(a1.y, we[5], mm);
    mm = fmaf(a1.z, we[6], mm);  mm = fmaf(a1.w, we[7], mm);
    mm = fmaf(a2.x, we[8], mm);  mm = fmaf(a2.y, we[9], mm);
    mm = fmaf(a2.z, we[10], mm); mm = fmaf(a2.w, we[11], mm);
    mm = fmaf(a3.x, we[12], mm); mm = fmaf(a3.y, we[13], mm);
    mm = fmaf(a3.z, we[14], mm); mm = fmaf(a3.w, we[15], mm);
    eesum += mm;                       // = eev + xr_n
    mm += xls;
    float p = fmaf(av08, fmaxf(mm, 0.f), av02 * mm);  // leaky(mm)*att*log2e
    p = head16_sum(p);                 // head logit, uniform in 16-lane group
    if (p > m + 11.5f) {               // rare: new max grew past threshold
      float sc = exp2f(m - p);
      acc = fmaf(acc, sc, xls);
      den = fmaf(den, sc, 1.f);
      m = p;
    } else {                           // common: single exp2, no rescale
      float w = exp2f(p - m);
      acc = fmaf(w, xls, acc);
      den += w;
    }
  };

  int j = j0;
  if ((j & 1) && j < j1) {             // peel to 16B-aligned pair boundary
    int2 es = csr2[j];
    int e = __builtin_amdgcn_readfirstlane(es.x);
    int s = __builtin_amdgcn_readfirstlane(es.y);
    edge_update(e, xl[(long)s * HC + ch]);
    ++j;
  }
  for (; j + 1 < j1; j += 2) {
    int4 q = *(const int4*)(csr2 + j);  // two (edge,src) pairs, one dwordx4
    int e0 = __builtin_amdgcn_readfirstlane(q.x);
    int s0 = __builtin_amdgcn_readfirstlane(q.y);
    int e1 = __builtin_amdgcn_readfirstlane(q.z);
    int s1 = __builtin_amdgcn_readfirstlane(q.w);
    float xls0 = xl[(long)s0 * HC + ch];
    float xls1 = xl[(long)s1 * HC + ch];
    edge_update(e0, xls0);
    edge_update(e1, xls1);
  }
  if (j < j1) {
    int2 es = csr2[j];
    int e = __builtin_amdgcn_readfirstlane(es.x);
    int s = __builtin_amdgcn_readfirstlane(es.y);
    edge_update(e, xl[(long)s * HC + ch]);
  }

  // ---- self-loop ----
  int deg = j1 - j0;
  float ee = (deg > 0) ? (eesum / (float)deg - xr_n) : 0.f;
  float mm = xl_n + xr_n + ee;
  float p = fmaf(av08, fmaxf(mm, 0.f), av02 * mm);
  p = head16_sum(p);
  if (p > m) {
    float sc = exp2f(m - p);
    acc = fmaf(acc, sc, xl_n);
    den = fmaf(den, sc, 1.f);
  } else {
    float w = exp2f(p - m);
    acc = fmaf(w, xl_n, acc);
    den += w;
  }

  out[n * HC + ch] = acc / den + bias[ch] + x[n * HC + ch];
}

// ---------- K6: GraphNorm segment sums (grid-parallel over group slices) ----------
#define GN_SLICES 32
__global__ void __launch_bounds__(128) gn_stats(
    const float* __restrict__ out, const int* __restrict__ gstart,
    float* __restrict__ gsum, float* __restrict__ gsq) {
  int g = blockIdx.x >> 5;
  int slice = blockIdx.x & 31;
  int s0 = gstart[g], s1 = gstart[g + 1];
  int cnt = s1 - s0;
  if (cnt <= 0) return;
  int chunk = (cnt + GN_SLICES - 1) / GN_SLICES;
  int lo = s0 + slice * chunk;
  int hi = lo + chunk; if (hi > s1) hi = s1;
  if (lo >= hi) return;
  int ch = threadIdx.x;
  float sum = 0.f, sq = 0.f;
  for (int nrow = lo; nrow < hi; ++nrow) {
    float v = out[(long)nrow * HC + ch];
    sum += v; sq += v * v;
  }
  atomicAdd(&gsum[g * HC + ch], sum);
  atomicAdd(&gsq[g * HC + ch], sq);
}

// ---------- K7: finalize mean / inv-std ----------
__global__ void gn_finalize(const float* __restrict__ gsum, const float* __restrict__ gsq,
                            const int* __restrict__ gstart, const float* __restrict__ gms,
                            float* __restrict__ msub, float* __restrict__ istd) {
  int t = blockIdx.x * 256 + threadIdx.x;
  if (t >= NG * HC) return;
  int g = t >> 7, ch = t & 127;
  float cnt = (float)(gstart[g + 1] - gstart[g]);
  if (cnt < 1.f) cnt = 1.f;
  float mean = gsum[t] / cnt;
  float c = gms[ch] * mean;              // the subtracted constant
  float ex2 = gsq[t] / cnt;
  float var = ex2 - 2.f * c * mean + c * c;   // E[(x-c)^2]
  msub[t] = c;
  istd[t] = rsqrtf(var + GEPS);
}

// ---------- K8: normalize + affine + ELU (float4) ----------
__global__ void gn_apply(float* __restrict__ out, const int* __restrict__ batch,
                         const float* __restrict__ msub, const float* __restrict__ istd,
                         const float* __restrict__ gnw, const float* __restrict__ gnb, int N) {
  long i = (long)blockIdx.x * 256 + threadIdx.x;     // float4 index
  if (i >= (long)N * 32) return;
  int c4 = (int)(i & 31);
  long n = i >> 5;
  int g = batch[n];
  float4 v = ((const float4*)out)[i];
  float4 ms = ((const float4*)msub)[g * 32 + c4];
  float4 is = ((const float4*)istd)[g * 32 + c4];
  float4 w  = ((const float4*)gnw)[c4];
  float4 b  = ((const float4*)gnb)[c4];
  float4 o;
  o.x = fmaf(w.x * (v.x - ms.x), is.x, b.x);
  o.y = fmaf(w.y * (v.y - ms.y), is.y, b.y);
  o.z = fmaf(w.z * (v.z - ms.z), is.z, b.z);
  o.w = fmaf(w.w * (v.w - ms.w), is.w, b.w);
  o.x = o.x > 0.f ? o.x : expm1f(o.x);
  o.y = o.y > 0.f ? o.y : expm1f(o.y);
  o.z = o.z > 0.f ? o.z : expm1f(o.z);
  o.w = o.w > 0.f ? o.w : expm1f(o.w);
  ((float4*)out)[i] = o;
}

extern "C" void kernel_launch(void* const* d_in, const int* in_sizes, int n_in,
                              void* d_out, int out_size, void* d_ws, size_t ws_size,
                              hipStream_t stream) {
  const float* x    = (const float*)d_in[0];
  const int*   ei   = (const int*)d_in[1];
  const float* ea   = (const float*)d_in[2];
  const int*   batch= (const int*)d_in[3];
  const float* Wl   = (const float*)d_in[4];
  const float* bl   = (const float*)d_in[5];
  const float* Wr   = (const float*)d_in[6];
  const float* br   = (const float*)d_in[7];
  const float* We   = (const float*)d_in[8];
  const float* att  = (const float*)d_in[9];
  const float* bias = (const float*)d_in[10];
  const float* gnw  = (const float*)d_in[11];
  const float* gnb  = (const float*)d_in[12];
  const float* gms  = (const float*)d_in[13];
  int N = in_sizes[0] / HC;
  int E = in_sizes[2] / EDIM;
  float* out = (float*)d_out;
  (void)n_in; (void)out_size; (void)ws_size;

  // ---- workspace carve-up (4-byte words, 16B aligned blocks) ----
  float* wsf = (float*)d_ws;
  size_t off = 0;
  auto alloc = [&](size_t words) -> float* {
    float* p = wsf + off;
    off += (words + 3) & ~(size_t)3;
    return p;
  };
  int*      deg     = (int*)alloc(N);
  float*    gsum    = alloc(NG * HC);
  float*    gsq     = alloc(NG * HC);
  int*      genc    = (int*)alloc(NG);
  size_t zero_words = off;                 // everything above starts at 0
  int*      gstart  = (int*)alloc(NG + 1);
  float*    msub    = alloc(NG * HC);
  float*    istd    = alloc(NG * HC);
  int*      bsum    = (int*)alloc(256);
  int*      bofs    = (int*)alloc(256);
  int*      offsets = (int*)alloc((size_t)N + 1);
  float*    xl      = alloc((size_t)N * HC);
  float*    xr      = alloc((size_t)N * HC);
  int2*     csr2    = (int2*)alloc((size_t)E * 2);

  int nb = (N + 255) / 256;   // scan blocks (<=256 by construction for N<=65536)

  zero_k<<<(unsigned)((zero_words + 255) / 256), 256, 0, stream>>>(wsf, zero_words);
  count_deg_mark<<<(E + 255) / 256, 256, 0, stream>>>(ei, deg, batch, genc, E, N);
  gemm_tiled<<<(N + GEMM_ROWS - 1) / GEMM_ROWS, 256, 0, stream>>>(x, Wl, bl, Wr, br, xl, xr, N);
  scan1<<<nb, 256, 0, stream>>>(deg, bsum, N);
  scan2<<<1, 1, 0, stream>>>(bsum, bofs, nb, offsets, N, genc, gstart);
  scan3<<<nb, 256, 0, stream>>>(deg, bofs, offsets, N);
  fill_csr<<<(E + 255) / 256, 256, 0, stream>>>(ei, deg, offsets, csr2, E);
  fused_node<<<N, 128, 0, stream>>>(offsets, csr2, ea, xl, xr, We, att, x, bias, out, N);
  gn_stats<<<NG * GN_SLICES, 128, 0, stream>>>(out, gstart, gsum, gsq);
  gn_finalize<<<(NG * HC + 255) / 256, 256, 0, stream>>>(gsum, gsq, gstart, gms, msub, istd);
  {
    long tot = (long)N * 32;
    gn_apply<<<(unsigned)((tot + 255) / 256), 256, 0, stream>>>(out, batch, msub, istd, gnw, gnb, N);
  }
}